// Round 3
// baseline (256.614 us; speedup 1.0000x reference)
//
#include <hip/hip_runtime.h>
#include <math.h>

#define NEGV  -10000000000.0f
#define LOG2E 1.44269504088896340736f
#define LN2F  0.69314718055994530942f

typedef float f4 __attribute__((ext_vector_type(4)));

constexpr int CS    = 32;          // diagonal steps per chunk
constexpr int ROWS  = 96;          // staged rows per wave window (need 95)
constexpr int CHW   = ROWS * 32;   // words per wave theta window (3072)
constexpr int KCMAX = 32;          // chunk count for N=M=512 (T=1023)
constexpr int SIT   = 48;          // global_load_lds per chunk (2 rows each)

// Staging is now DIRECT HBM->LDS via global_load_lds: no register round-trip,
// so the per-chunk "wait vmcnt for the whole 48-load burst before ds_write"
// coupling (the suspected invariant ~5000-cyc critical-path stall) is gone.
// Loads for chunk c+1 are issued right after chunk c's theta ds_reads have
// completed (one lgkmcnt(0)); a single vmcnt(0) at chunk end drains them, so
// a full chunk of compute covers the HBM latency.
// LDS layout: [row][slot] with slot = (col + row) & 31 (source-address
// rotation, linear LDS dest). Read bank = (2k + 63 - l) & 31 -> lanes l and
// l+32 alias = 2-way conflict = free. theta*LOG2E is folded into the cell as
// fmaf(th, LOG2E, mx) - zero extra ops.
__global__ __launch_bounds__(512, 2) void nw_kernel(
    const float* __restrict__ theta, const float* __restrict__ A,
    float* __restrict__ out, int N, int M)
{
    __shared__ float thS[8 * CHW];             //  98,304 B (wave-private)
    __shared__ float bndD[9 * KCMAX * CS];     //  36,864 B boundary history
    __shared__ int   flg[9 * KCMAX];           //   1,152 B

    const int tid = threadIdx.x;
    const int w   = tid >> 6;
    const int l   = tid & 63;
    const int j   = tid;                 // owns column j+1
    const int b   = blockIdx.x;
    const int NW  = blockDim.x >> 6;

    // zero flags; the ONLY block-wide barrier in the kernel
    for (int i = tid; i < 9 * KCMAX; i += blockDim.x) flg[i] = 0;
    __syncthreads();

    const float a2 = A[b] * LOG2E;
    const float* __restrict__ thb = theta + (size_t)b * N * M;
    const int NM = N * M;

    const int T  = N + M - 1;
    const int KC = (T + CS - 1) / CS;
    const int wstart = 64 * w;
    const int wend   = 64 * w + 63 + N - 1;
    const int ca = wstart / CS;                     // first chunk this wave computes
    const int cb = min(KC - 1, wend / CS);          // last chunk

    // lane constants
    const int l5  = l >> 5, l31 = l & 31;
    const int q2  = l31 - l5;            // staging: slot->col rotation term
    const int q   = 63 - l;              // read row offset
    float* thW = &thS[w * CHW];

    // issue 48 direct global->LDS loads for chunk cn (2 rows / 64 words each).
    // LDS word (r, s) receives theta[rb+r][64w+63 + ((s-r)&31) - r]; lane l of
    // iteration it supplies (r = 2it + l>>5, s = l&31), so its source column
    // index is c = ((l&31) - r) & 31.
    auto issue_stage = [&](int cn) {
        const int rb = CS * cn - 64 * w - 63;
        const int gbase = rb * M + 64 * w + 63;
        if (rb >= 0 && rb + (ROWS - 1) <= N - 1) {
            #pragma unroll
            for (int it = 0; it < SIT; ++it) {
                const int r = 2 * it + l5;
                const int c = (q2 - 2 * it) & 31;
                const int gidx = gbase + r * (M - 1) + c;
                __builtin_amdgcn_global_load_lds(
                    (const __attribute__((address_space(1))) void*)(thb + gidx),
                    (__attribute__((address_space(3))) void*)(thW + it * 64),
                    4, 0, 0);
            }
        } else {
            #pragma unroll
            for (int it = 0; it < SIT; ++it) {
                const int r = 2 * it + l5;
                const int c = (q2 - 2 * it) & 31;
                int gidx = gbase + r * (M - 1) + c;
                gidx = min(max(gidx, 0), NM - 1);   // garbage lands only on
                __builtin_amdgcn_global_load_lds(   // inactive cells
                    (const __attribute__((address_space(1))) void*)(thb + gidx),
                    (__attribute__((address_space(3))) void*)(thW + it * 64),
                    4, 0, 0);
            }
        }
    };
    auto wait_flag = [&](int idx) {
        if (__atomic_load_n(&flg[idx], __ATOMIC_ACQUIRE) == 0) {
            do { __builtin_amdgcn_s_sleep(1); }
            while (__atomic_load_n(&flg[idx], __ATOMIC_ACQUIRE) == 0);
        }
    };

    // pair state: value = m + log2(s)
    float mp = NEGV, sp = 1.0f;                    // own previous value
    float md = (j == 0) ? 0.0f : NEGV, sd = 1.0f;  // diag (left neighbor, -2 steps)
    float bcarry = NEGV;                           // boundary value, step CS*c - 1

    // prologue: theta for first chunk must be resident before its ds_reads
    issue_stage(ca);
    __asm__ volatile("s_waitcnt vmcnt(0)" ::: "memory");
    if (w > 0) {                            // bcarry for first chunk is real data
        wait_flag(w * KCMAX + (ca - 1));
        bcarry = bndD[(w * KCMAX + ca - 1) * CS + (CS - 1)];
    }

    for (int c = ca; c <= cb; ++c) {
        // first 8 theta reads early (latency overlaps flag spin)
        float th[CS];
        #pragma unroll
        for (int k = 0; k < 8; ++k)
            th[k] = thW[32 * (q + k) + ((2 * k + q) & 31)];

        // neighbor boundary — only while this wave's lane 0 is still active
        const bool need_bv = (w > 0) && (CS * c <= 64 * w + N - 1);
        float bv[CS];
        if (need_bv) {
            wait_flag(w * KCMAX + c);
            const f4* src = (const f4*)&bndD[(w * KCMAX + c) * CS];
            #pragma unroll
            for (int qd = 0; qd < CS / 4; ++qd) {
                f4 t = src[qd];
                bv[4*qd+0] = t.x; bv[4*qd+1] = t.y;
                bv[4*qd+2] = t.z; bv[4*qd+3] = t.w;
            }
        } else {
            #pragma unroll
            for (int k = 0; k < CS; ++k) bv[k] = NEGV;
        }

        #pragma unroll
        for (int k = 8; k < CS; ++k)
            th[k] = thW[32 * (q + k) + ((2 * k + q) & 31)];

        // all LDS reads (th into regs) must COMPLETE before the direct loads
        // can start overwriting the theta window (async land, no DS ordering)
        __asm__ volatile("s_waitcnt lgkmcnt(0)" ::: "memory");
        if (c + 1 <= cb) issue_stage(c + 1);

        float res[CS];
        const bool full = (CS * c >= 64 * w + 63) &&
                          (CS * c + CS - 1 <= 64 * w + N - 1);
        if (full) {
            #pragma unroll
            for (int k = 0; k < CS; ++k) {
                float bm = (k == 0) ? bcarry : bv[k - 1];
                float ml = __int_as_float(__builtin_amdgcn_update_dpp(
                    __float_as_int(bm), __float_as_int(mp),
                    0x138 /* wave_shr:1 */, 0xF, 0xF, false));
                float sl = __int_as_float(__builtin_amdgcn_update_dpp(
                    0x3f800000 /* 1.0f */, __float_as_int(sp),
                    0x138, 0xF, 0xF, false));
                float u  = a2 + mp;
                float ul = a2 + ml;
                float mx = fmaxf(fmaxf(u, md), ul);       // v_max3_f32
                float e1 = __builtin_amdgcn_exp2f(u  - mx);
                float e2 = __builtin_amdgcn_exp2f(md - mx);
                float e3 = __builtin_amdgcn_exp2f(ul - mx);
                float sn = fmaf(sl, e3, fmaf(sd, e2, sp * e1));
                float mn = fmaf(th[k], LOG2E, mx);
                res[k] = mn + __builtin_amdgcn_logf(sn);  // collapse (off-chain)
                md = ml; sd = sl;
                mp = mn; sp = sn;
            }
        } else {
            const int tmj = CS * c - j;
            #pragma unroll
            for (int k = 0; k < CS; ++k) {
                float bm = (k == 0) ? bcarry : bv[k - 1];
                float ml = __int_as_float(__builtin_amdgcn_update_dpp(
                    __float_as_int(bm), __float_as_int(mp),
                    0x138, 0xF, 0xF, false));
                float sl = __int_as_float(__builtin_amdgcn_update_dpp(
                    0x3f800000, __float_as_int(sp),
                    0x138, 0xF, 0xF, false));
                float u  = a2 + mp;
                float ul = a2 + ml;
                float mx = fmaxf(fmaxf(u, md), ul);
                float e1 = __builtin_amdgcn_exp2f(u  - mx);
                float e2 = __builtin_amdgcn_exp2f(md - mx);
                float e3 = __builtin_amdgcn_exp2f(ul - mx);
                float sn = fmaf(sl, e3, fmaf(sd, e2, sp * e1));
                float mn = fmaf(th[k], LOG2E, mx);
                int dt = tmj + k;            // t - j; active iff 0 <= dt < N
                bool act = (unsigned)dt < (unsigned)N;
                float mq = act ? mn : (dt < 0 ? NEGV : mp);
                float sq2 = act ? sn : (dt < 0 ? 1.0f : sp);
                res[k] = mq + __builtin_amdgcn_logf(sq2);
                md = ml; sd = sl;
                mp = mq; sp = sq2;
            }
        }

        // publish boundary to next wave, then release the flag
        if (w < NW - 1 && l == 63) {
            f4* dst = (f4*)&bndD[((w + 1) * KCMAX + c) * CS];
            #pragma unroll
            for (int qd = 0; qd < CS / 4; ++qd)
                dst[qd] = (f4){res[4*qd+0], res[4*qd+1], res[4*qd+2], res[4*qd+3]};
            __atomic_store_n(&flg[(w + 1) * KCMAX + c], 1, __ATOMIC_RELEASE);
        }
        bcarry = bv[CS - 1];

        // exact renorm: fold exponent of s into m (bounds s without rounding)
        {
            int bs = __float_as_int(sp);
            int ex = ((bs >> 23) & 0xff) - 127;
            sp = __int_as_float(bs - (ex << 23));
            mp += (float)ex;
            int bd = __float_as_int(sd);
            int ed = ((bd >> 23) & 0xff) - 127;
            sd = __int_as_float(bd - (ed << 23));
            md += (float)ed;
        }

        // drain the direct loads for chunk c+1 before next chunk's th reads
        __asm__ volatile("s_waitcnt vmcnt(0)" ::: "memory");
    }

    if (j == M - 1)
        out[b] = (mp + __builtin_amdgcn_logf(sp)) * LN2F;  // back to ln domain
}

extern "C" void kernel_launch(void* const* d_in, const int* in_sizes, int n_in,
                              void* d_out, int out_size, void* d_ws, size_t ws_size,
                              hipStream_t stream) {
    const float* theta = (const float*)d_in[0];
    const float* A     = (const float*)d_in[1];
    float* out = (float*)d_out;

    const int B  = in_sizes[1];
    const int NM = in_sizes[0] / B;
    int N = 1;
    while (N * N < NM) N <<= 1;   // 512x512 expected
    const int M = NM / N;

    hipLaunchKernelGGL(nw_kernel, dim3(B), dim3(M), 0, stream,
                       theta, A, out, N, M);
}

// Round 6
// 203.244 us; speedup vs baseline: 1.2626x; 1.2626x over previous
//
#include <hip/hip_runtime.h>
#include <math.h>

#define NEGV  -10000000000.0f
#define LOG2E 1.44269504088896340736f
#define LN2F  0.69314718055994530942f

typedef float f4 __attribute__((ext_vector_type(4)));

constexpr int CS    = 32;          // diagonal steps per chunk
constexpr int ROWS  = 96;          // staged rows per wave window (need 95)
constexpr int WL    = 33;          // LDS words per row (32 data + 1 pad)
constexpr int CHW   = ROWS * WL;   // words per wave theta window (3168)
constexpr int KCMAX = 32;          // chunk count for N=M=512 (T=1023)
constexpr int SIT   = 48;          // staging iterations (2 rows x 32 cols)

// TWO blocks per batch, 256 threads (4 waves) each -> 1 wave per SIMD.
// Rounds 0-2 showed the cadence is per-wave wall time inflated ~2x by TWO
// co-resident waves sharing each SIMD's issue (43% VALUBusy on active CUs,
// three different inner loops all at ~117us). This split removes the sharing
// without touching the (absmax-0.0 proven) round-2 pair-state math.
// Intra-block wave handoff: LDS flags + boundary rows, as before.
// Cross-block seam (global wave 3 -> 4, once per batch): workspace ring of
// 32 log-domain floats + flag per chunk, agent-scope atomics (correct across
// non-coherent XCD L2s). Seam latency enters the pipeline once, not per chunk.
__global__ __launch_bounds__(256, 1) void nw_kernel(
    const float* __restrict__ theta, const float* __restrict__ A,
    float* __restrict__ out, int* __restrict__ flagsG,
    float* __restrict__ dataG, int N, int M)
{
    __shared__ float thS[4 * CHW];             // 50,688 B (wave-private)
    __shared__ float bndL[4 * KCMAX * CS];     // 16,384 B intra-block boundaries
    __shared__ int   flgL[4 * KCMAX];          //    512 B

    const int tid = threadIdx.x;
    const int wl  = tid >> 6;            // local wave 0..3
    const int l   = tid & 63;
    const int h   = blockIdx.x & 1;      // which half of the batch
    const int b   = blockIdx.x >> 1;
    const int W   = 4 * h + wl;          // global wave 0..7
    const int j   = 256 * h + tid;       // owns column j+1

    for (int i = tid; i < 4 * KCMAX; i += blockDim.x) flgL[i] = 0;
    __syncthreads();                     // the ONLY block-wide barrier

    const float a2 = A[b] * LOG2E;
    const float* __restrict__ thb = theta + (size_t)b * N * M;
    const int NM = N * M;
    int* __restrict__ gflag   = flagsG + b * KCMAX;
    float* __restrict__ gdata = dataG + (size_t)b * KCMAX * CS;

    const int T  = N + M - 1;
    const int KC = (T + CS - 1) / CS;
    const int ca = 2 * W;                                // first chunk
    const int cb = min(KC - 1, (64 * W + 63 + N - 1) / CS);

    // staging lane constants: 48 iterations x (2 rows x 32 cols)
    const int srow = l >> 5;
    const int sq   = l & 31;
    const int lanebase = srow * (M - 1) + 64 * W + 63 + sq;
    const int wrbase   = wl * CHW + srow * WL + sq;
    const int rdbase   = wl * CHW + (63 - l) * WL;

    auto stage_load = [&](int cn, float* stg) {
        const int rb = CS * cn - 64 * W - 63;
        if (rb >= 0 && rb + (ROWS - 1) <= N - 1) {
            const float* p = thb + (size_t)rb * M;
            #pragma unroll
            for (int it = 0; it < SIT; ++it) { stg[it] = p[lanebase]; p += 2 * (M - 1); }
        } else {
            const int rbM = rb * M;
            #pragma unroll
            for (int it = 0; it < SIT; ++it) {
                int off = rbM + lanebase + it * 2 * (M - 1);
                off = min(max(off, 0), NM - 1);
                stg[it] = thb[off];
            }
        }
    };
    auto stage_write = [&](const float* stg) {
        #pragma unroll
        for (int it = 0; it < SIT; ++it) thS[wrbase + it * 2 * WL] = stg[it] * LOG2E;
    };
    auto wait_flag_lds = [&](int idx) {
        if (__atomic_load_n(&flgL[idx], __ATOMIC_ACQUIRE) == 0) {
            do { __builtin_amdgcn_s_sleep(1); }
            while (__atomic_load_n(&flgL[idx], __ATOMIC_ACQUIRE) == 0);
        }
    };
    auto wait_flag_glb = [&](int c) {
        if (__hip_atomic_load(&gflag[c], __ATOMIC_ACQUIRE,
                              __HIP_MEMORY_SCOPE_AGENT) == 0) {
            do { __builtin_amdgcn_s_sleep(2); }
            while (__hip_atomic_load(&gflag[c], __ATOMIC_ACQUIRE,
                                     __HIP_MEMORY_SCOPE_AGENT) == 0);
        }
    };

    float v_prev = NEGV;                    // V2[i][j+1] running value
    float v_diag = (j == 0) ? 0.0f : NEGV;  // V2[0][0] = 0 seeds thread 0
    float bcarry = NEGV;                    // neighbor boundary, step CS*c - 1

    {   // prologue staging (self-consumed; intra-wave ordering)
        float s0[SIT];
        stage_load(ca, s0);
        stage_write(s0);
        __asm__ volatile("s_waitcnt lgkmcnt(0)" ::: "memory");
    }
    if (W > 0) {                            // bcarry for first chunk
        const int cp = ca - 1;
        if (wl > 0) {
            wait_flag_lds(wl * KCMAX + cp);
            bcarry = bndL[(wl * KCMAX + cp) * CS + (CS - 1)];
        } else {                            // h==1, W==4: global seam
            wait_flag_glb(cp);
            bcarry = __hip_atomic_load(&gdata[cp * CS + (CS - 1)],
                                       __ATOMIC_RELAXED, __HIP_MEMORY_SCOPE_AGENT);
        }
    }

    float stg[SIT];
    bool have = (ca + 1 <= cb);
    if (have) stage_load(ca + 1, stg);

    const bool pub = (W < 7);

    for (int c = ca; c <= cb; ++c) {
        // first 8 theta reads early (latency overlaps flag spin)
        float th[CS];
        #pragma unroll
        for (int k = 0; k < 8; ++k) th[k] = thS[rdbase + k * (WL + 1)];

        // neighbor boundary — only while this wave's lane 0 is still active
        const bool need_bv = (W > 0) && (CS * c <= 64 * W + N - 1);
        float bv[CS];
        if (need_bv) {
            if (wl > 0) {
                wait_flag_lds(wl * KCMAX + c);
                const f4* src = (const f4*)&bndL[(wl * KCMAX + c) * CS];
                #pragma unroll
                for (int q = 0; q < CS / 4; ++q) {
                    f4 t = src[q];
                    bv[4*q+0] = t.x; bv[4*q+1] = t.y;
                    bv[4*q+2] = t.z; bv[4*q+3] = t.w;
                }
            } else {                        // h==1, W==4: global seam
                wait_flag_glb(c);
                #pragma unroll
                for (int k = 0; k < CS; ++k)
                    bv[k] = __hip_atomic_load(&gdata[c * CS + k],
                                              __ATOMIC_RELAXED,
                                              __HIP_MEMORY_SCOPE_AGENT);
            }
        } else {
            #pragma unroll
            for (int k = 0; k < CS; ++k) bv[k] = NEGV;
        }

        #pragma unroll
        for (int k = 8; k < CS; ++k) th[k] = thS[rdbase + k * (WL + 1)];

        float res[CS];
        const bool full = (CS * c >= 64 * W + 63) &&
                          (CS * c + CS - 1 <= 64 * W + N - 1);
        if (full) {
            #pragma unroll
            for (int k = 0; k < CS; ++k) {
                float bk = (k == 0) ? bcarry : bv[k - 1];
                float vl = __int_as_float(__builtin_amdgcn_update_dpp(
                    __float_as_int(bk), __float_as_int(v_prev),
                    0x138 /* wave_shr:1 */, 0xF, 0xF, false));
                float x = a2 + v_prev;
                float z = a2 + vl;
                float m = fmaxf(fmaxf(x, v_diag), z);
                float s = __builtin_amdgcn_exp2f(x - m)
                        + __builtin_amdgcn_exp2f(v_diag - m)
                        + __builtin_amdgcn_exp2f(z - m);
                float v = th[k] + m + __builtin_amdgcn_logf(s);
                res[k] = v;
                v_diag = vl;
                v_prev = v;
            }
        } else {
            const int tmj = CS * c - j;
            #pragma unroll
            for (int k = 0; k < CS; ++k) {
                float bk = (k == 0) ? bcarry : bv[k - 1];
                float vl = __int_as_float(__builtin_amdgcn_update_dpp(
                    __float_as_int(bk), __float_as_int(v_prev),
                    0x138, 0xF, 0xF, false));
                float x = a2 + v_prev;
                float z = a2 + vl;
                float m = fmaxf(fmaxf(x, v_diag), z);
                float s = __builtin_amdgcn_exp2f(x - m)
                        + __builtin_amdgcn_exp2f(v_diag - m)
                        + __builtin_amdgcn_exp2f(z - m);
                float v = th[k] + m + __builtin_amdgcn_logf(s);
                int dt = tmj + k;            // t - j; active iff 0 <= dt < N
                float vn = ((unsigned)dt < (unsigned)N) ? v
                                                        : (dt < 0 ? NEGV : v_prev);
                res[k] = vn;
                v_diag = vl;
                v_prev = vn;
            }
        }

        // publish boundary to next wave, then release the flag
        if (pub && l == 63) {
            if (wl < 3) {                   // intra-block seam (LDS)
                f4* dst = (f4*)&bndL[((wl + 1) * KCMAX + c) * CS];
                #pragma unroll
                for (int q = 0; q < CS / 4; ++q)
                    dst[q] = (f4){res[4*q+0], res[4*q+1], res[4*q+2], res[4*q+3]};
                __atomic_store_n(&flgL[(wl + 1) * KCMAX + c], 1, __ATOMIC_RELEASE);
            } else {                        // h==0, W==3: global seam
                #pragma unroll
                for (int k = 0; k < CS; ++k)
                    __hip_atomic_store(&gdata[c * CS + k], res[k],
                                       __ATOMIC_RELAXED, __HIP_MEMORY_SCOPE_AGENT);
                __hip_atomic_store(&gflag[c], 1,
                                   __ATOMIC_RELEASE, __HIP_MEMORY_SCOPE_AGENT);
            }
        }
        bcarry = bv[CS - 1];

        // write staged theta for c+1, issue loads for c+2
        if (have) stage_write(stg);
        have = (c + 2 <= cb);
        if (have) stage_load(c + 2, stg);
        __asm__ volatile("s_waitcnt lgkmcnt(0)" ::: "memory");
    }

    if (j == M - 1) out[b] = v_prev * LN2F;   // V[N][M], back to ln domain
}

extern "C" void kernel_launch(void* const* d_in, const int* in_sizes, int n_in,
                              void* d_out, int out_size, void* d_ws, size_t ws_size,
                              hipStream_t stream) {
    const float* theta = (const float*)d_in[0];
    const float* A     = (const float*)d_in[1];
    float* out = (float*)d_out;

    const int B  = in_sizes[1];
    const int NM = in_sizes[0] / B;
    int N = 1;
    while (N * N < NM) N <<= 1;   // 512x512 expected
    const int M = NM / N;

    // workspace: [B*KCMAX int flags][B*KCMAX*CS float boundary records]
    int*   flagsG = (int*)d_ws;
    float* dataG  = (float*)((char*)d_ws + (size_t)B * KCMAX * sizeof(int));
    hipMemsetAsync(d_ws, 0, (size_t)B * KCMAX * sizeof(int), stream);

    hipLaunchKernelGGL(nw_kernel, dim3(2 * B), dim3(256), 0, stream,
                       theta, A, out, flagsG, dataG, N, M);
}